// Round 2
// baseline (635.313 us; speedup 1.0000x reference)
//
#include <hip/hip_runtime.h>
#include <hip/hip_bf16.h>

// Problem dims
#define B_ 256
#define L_ 100
#define F_ 8
#define P_ 4
#define E_ 64
#define H_ 4
#define D_ 64
#define C_ 32
#define V_ 10000
#define HD_ 256
#define TOWER_IN_ 1312
#define LN_EPS 0.001f
#define LC_ 5   // l's per attention block

// ---------------------------------------------------------------------------
// Kernel P: precompute M_lh = Qh @ Kh^T and W_lh = Vh @ Lh  (64x64 each, f32)
// grid = L*H = 400 blocks, 256 threads
// ---------------------------------------------------------------------------
__global__ __launch_bounds__(256) void precomp_kernel(
    const float* __restrict__ q_w, const float* __restrict__ k_w,
    const float* __restrict__ v_w, const float* __restrict__ lin_w,
    float* __restrict__ wsM, float* __restrict__ wsW)
{
    __shared__ float sA[64][65];
    __shared__ float sB[64][65];
    const int t = threadIdx.x;
    const int l = blockIdx.x >> 2;
    const int h = blockIdx.x & 3;

    // ---- phase 1: M = Qh @ Kh^T -------------------------------------------
    for (int i = 0; i < 16; ++i) {
        int idx = t + i * 256;
        int e = idx >> 6, d = idx & 63;
        sA[e][d] = q_w[(l * 64 + e) * 256 + h * 64 + d];
        sB[e][d] = k_w[(l * 64 + e) * 256 + h * 64 + d];
    }
    __syncthreads();
    for (int i = 0; i < 16; ++i) {
        int idx = t + i * 256;
        int e1 = idx >> 6, e2 = idx & 63;
        float s = 0.f;
        #pragma unroll 8
        for (int d = 0; d < 64; ++d) s += sA[e1][d] * sB[e2][d];
        wsM[(l * 4 + h) * 4096 + idx] = s;
    }
    __syncthreads();

    // ---- phase 2: W = Vh @ Lh ---------------------------------------------
    for (int i = 0; i < 16; ++i) {
        int idx = t + i * 256;
        int e = idx >> 6, d = idx & 63;
        sA[e][d] = v_w[(l * 64 + e) * 256 + h * 64 + d];          // Vh[e][d]
        sB[e][d] = lin_w[l * 16384 + (h * 64 + e) * 64 + d];      // Lh[e][d]
    }
    __syncthreads();
    for (int i = 0; i < 16; ++i) {
        int idx = t + i * 256;
        int e1 = idx >> 6, e2 = idx & 63;
        float s = 0.f;
        #pragma unroll 8
        for (int d = 0; d < 64; ++d) s += sA[e1][d] * sB[d][e2];
        wsW[(l * 4 + h) * 4096 + idx] = s;
    }
}

// ---------------------------------------------------------------------------
// Kernel A: fused attention per (b, chunk of 5 l's).
// grid = 20*256 blocks (bid = c*256 + b), 256 threads = 4 waves (wave == h)
// ---------------------------------------------------------------------------
__global__ __launch_bounds__(256) void attn_kernel(
    const int* __restrict__ ubs_feature, const float* __restrict__ item_tables,
    const float* __restrict__ wsM, const float* __restrict__ wsW,
    const float* __restrict__ lin_b, const float* __restrict__ ln_g,
    const float* __restrict__ ln_b, float* __restrict__ ubs_acc)
{
    __shared__ float sUE[F_][65];
    __shared__ float sT[H_][F_][65];   // reused as per-h partials later
    __shared__ float sZ[H_][F_][65];
    __shared__ float sAttw[H_][F_][8];
    __shared__ float sAcc[F_][64];

    const int t = threadIdx.x;
    const int c = blockIdx.x >> 8;     // 0..19
    const int b = blockIdx.x & 255;
    const int wave = t >> 6;           // == h
    const int lane = t & 63;

    for (int i = t; i < F_ * 64; i += 256) (&sAcc[0][0])[i] = 0.f;
    __syncthreads();

    for (int li = 0; li < LC_; ++li) {
        const int l = c * LC_ + li;

        // gather ue[b,l] : 8x64
        for (int i = t; i < 512; i += 256) {
            int f = i >> 6, e = i & 63;
            int vidx = ubs_feature[(b * L_ + l) * F_ + f];
            sUE[f][e] = item_tables[(f * V_ + vidx) * 64 + e];
        }
        __syncthreads();

        // T_h = ue @ M_lh ; Z_h = ue @ W_lh   (h = wave, o = lane)
        {
            const float* M = wsM + (l * 4 + wave) * 4096;
            const float* W = wsW + (l * 4 + wave) * 4096;
            float accT[F_], accZ[F_];
            #pragma unroll
            for (int f = 0; f < F_; ++f) { accT[f] = 0.f; accZ[f] = 0.f; }
            for (int e = 0; e < 64; ++e) {
                float m = M[e * 64 + lane];
                float w = W[e * 64 + lane];
                #pragma unroll
                for (int f = 0; f < F_; ++f) {
                    float u = sUE[f][e];
                    accT[f] += u * m;
                    accZ[f] += u * w;
                }
            }
            #pragma unroll
            for (int f = 0; f < F_; ++f) { sT[wave][f][lane] = accT[f]; sZ[wave][f][lane] = accZ[f]; }
        }
        __syncthreads();

        // scores_h = (T_h @ ue^T)/8 ; softmax over g  (f = lane>>3, g = lane&7)
        {
            int f = lane >> 3, g = lane & 7;
            float s = 0.f;
            #pragma unroll 8
            for (int e = 0; e < 64; ++e) s += sT[wave][f][e] * sUE[g][e];
            s *= 0.125f;
            float mx = s;
            #pragma unroll
            for (int m = 1; m < 8; m <<= 1) mx = fmaxf(mx, __shfl_xor(mx, m, 8));
            float ex = __expf(s - mx);
            float sum = ex;
            #pragma unroll
            for (int m = 1; m < 8; m <<= 1) sum += __shfl_xor(sum, m, 8);
            sAttw[wave][f][g] = ex / sum;
        }
        __syncthreads();

        // part_h = attw_h @ Z_h  -> overwrite sT
        {
            float z[F_];
            #pragma unroll
            for (int g = 0; g < F_; ++g) z[g] = sZ[wave][g][lane];
            #pragma unroll
            for (int f = 0; f < F_; ++f) {
                float s = 0.f;
                #pragma unroll
                for (int g = 0; g < F_; ++g) s += sAttw[wave][f][g] * z[g];
                sT[wave][f][lane] = s;
            }
        }
        __syncthreads();

        // sum over h, + lin_b, LayerNorm over e, accumulate over l
        {
            float lb = lin_b[l * 64 + lane];
            float gg = ln_g[lane];
            float bb = ln_b[lane];
            #pragma unroll
            for (int r = 0; r < 2; ++r) {
                int f = wave + r * 4;
                float v = sT[0][f][lane] + sT[1][f][lane] + sT[2][f][lane] + sT[3][f][lane] + lb;
                float s = v;
                #pragma unroll
                for (int m = 1; m < 64; m <<= 1) s += __shfl_xor(s, m, 64);
                float mean = s * (1.f / 64.f);
                float d = v - mean;
                float q = d * d;
                #pragma unroll
                for (int m = 1; m < 64; m <<= 1) q += __shfl_xor(q, m, 64);
                float var = q * (1.f / 64.f);
                sAcc[f][lane] += d * rsqrtf(var + LN_EPS) * gg + bb;
            }
        }
        __syncthreads();
    }

    for (int i = t; i < 512; i += 256) {
        int f = i >> 6, e = i & 63;
        atomicAdd(&ubs_acc[(b * F_ + f) * 64 + e], sAcc[f][e]);
    }
}

// ---------------------------------------------------------------------------
// block-wide sum over 256 threads (4 waves)
// ---------------------------------------------------------------------------
__device__ __forceinline__ float block_reduce_sum(float v, float* sRed) {
    #pragma unroll
    for (int m = 1; m < 64; m <<= 1) v += __shfl_xor(v, m, 64);
    int wave = threadIdx.x >> 6, lane = threadIdx.x & 63;
    __syncthreads();                   // protect previous use of sRed
    if (lane == 0) sRed[wave] = v;
    __syncthreads();
    return sRed[0] + sRed[1] + sRed[2] + sRed[3];
}

// ---------------------------------------------------------------------------
// Kernel T: gather/concat + 4-layer tower with LN+ReLU, sigmoid out.
// grid = 256 blocks (one per b), 256 threads
// ---------------------------------------------------------------------------
__global__ __launch_bounds__(256) void tower_kernel(
    const float* __restrict__ ubs_acc,
    const int* __restrict__ target_ad, const int* __restrict__ profile_feature,
    const float* __restrict__ context,
    const float* __restrict__ item_tables, const float* __restrict__ profile_tables,
    const float* __restrict__ w1, const float* __restrict__ b1,
    const float* __restrict__ g1, const float* __restrict__ bb1,
    const float* __restrict__ w2, const float* __restrict__ b2,
    const float* __restrict__ g2, const float* __restrict__ bb2,
    const float* __restrict__ w3, const float* __restrict__ b3,
    const float* __restrict__ g3, const float* __restrict__ bb3,
    const float* __restrict__ w4, const float* __restrict__ b4,
    float* __restrict__ out)
{
    __shared__ float sX[TOWER_IN_];
    __shared__ float sH[1024];
    __shared__ float sRed[4];
    const int t = threadIdx.x;
    const int b = blockIdx.x;

    // build concat input: [ubs(512) | te(512) | pe(256) | ctx(32)]
    for (int i = t; i < TOWER_IN_; i += 256) {
        float v;
        if (i < 512) {
            v = fmaxf(ubs_acc[b * 512 + i] * 0.01f, 0.f);
        } else if (i < 1024) {
            int j = i - 512; int f = j >> 6, e = j & 63;
            v = item_tables[(f * V_ + target_ad[b * F_ + f]) * 64 + e];
        } else if (i < 1280) {
            int j = i - 1024; int p = j >> 6, e = j & 63;
            v = profile_tables[(p * V_ + profile_feature[b * P_ + p]) * 64 + e];
        } else {
            v = context[b * C_ + (i - 1280)];
        }
        sX[i] = v;
    }
    __syncthreads();

    // ---- layer 1: 1312 -> 1024, LN, ReLU ----------------------------------
    {
        float y[4];
        #pragma unroll
        for (int r = 0; r < 4; ++r) y[r] = b1[t + r * 256];
        for (int i = 0; i < TOWER_IN_; ++i) {
            float x = sX[i];
            const float* wrow = w1 + i * 1024 + t;
            #pragma unroll
            for (int r = 0; r < 4; ++r) y[r] += x * wrow[r * 256];
        }
        float s = y[0] + y[1] + y[2] + y[3];
        s = block_reduce_sum(s, sRed);
        float mean = s * (1.f / 1024.f);
        float q = 0.f;
        #pragma unroll
        for (int r = 0; r < 4; ++r) { float d = y[r] - mean; q += d * d; }
        q = block_reduce_sum(q, sRed);
        float rst = rsqrtf(q * (1.f / 1024.f) + LN_EPS);
        #pragma unroll
        for (int r = 0; r < 4; ++r) {
            int j = t + r * 256;
            sH[j] = fmaxf((y[r] - mean) * rst * g1[j] + bb1[j], 0.f);
        }
    }
    __syncthreads();

    // ---- layer 2: 1024 -> 512, LN, ReLU (into sX[0:512]) ------------------
    {
        float y[2];
        #pragma unroll
        for (int r = 0; r < 2; ++r) y[r] = b2[t + r * 256];
        for (int i = 0; i < 1024; ++i) {
            float x = sH[i];
            const float* wrow = w2 + i * 512 + t;
            #pragma unroll
            for (int r = 0; r < 2; ++r) y[r] += x * wrow[r * 256];
        }
        float s = y[0] + y[1];
        s = block_reduce_sum(s, sRed);
        float mean = s * (1.f / 512.f);
        float q = 0.f;
        #pragma unroll
        for (int r = 0; r < 2; ++r) { float d = y[r] - mean; q += d * d; }
        q = block_reduce_sum(q, sRed);
        float rst = rsqrtf(q * (1.f / 512.f) + LN_EPS);
        #pragma unroll
        for (int r = 0; r < 2; ++r) {
            int j = t + r * 256;
            sX[j] = fmaxf((y[r] - mean) * rst * g2[j] + bb2[j], 0.f);
        }
    }
    __syncthreads();

    // ---- layer 3: 512 -> 256, LN, ReLU (into sH[0:256]) -------------------
    {
        float y = b3[t];
        for (int i = 0; i < 512; ++i) y += sX[i] * w3[i * 256 + t];
        float s = block_reduce_sum(y, sRed);
        float mean = s * (1.f / 256.f);
        float d = y - mean;
        float q = block_reduce_sum(d * d, sRed);
        float rst = rsqrtf(q * (1.f / 256.f) + LN_EPS);
        float h = d * rst * g3[t] + bb3[t];
        sH[t] = fmaxf(h, 0.f);
    }
    __syncthreads();

    // ---- layer 4: 256 -> 1, sigmoid ---------------------------------------
    {
        float p = sH[t] * w4[t];
        float s = block_reduce_sum(p, sRed);
        if (t == 0) {
            float y = s + b4[0];
            out[b] = 1.f / (1.f + expf(-y));
        }
    }
}

// ---------------------------------------------------------------------------
extern "C" void kernel_launch(void* const* d_in, const int* in_sizes, int n_in,
                              void* d_out, int out_size, void* d_ws, size_t ws_size,
                              hipStream_t stream)
{
    (void)in_sizes; (void)n_in; (void)out_size; (void)ws_size;
    const int*   target_ad       = (const int*)d_in[0];
    const int*   ubs_feature     = (const int*)d_in[1];
    const int*   profile_feature = (const int*)d_in[2];
    const float* context         = (const float*)d_in[3];
    const float* item_tables     = (const float*)d_in[4];
    const float* profile_tables  = (const float*)d_in[5];
    const float* q_w   = (const float*)d_in[6];
    const float* k_w   = (const float*)d_in[7];
    const float* v_w   = (const float*)d_in[8];
    const float* lin_w = (const float*)d_in[9];
    const float* lin_b = (const float*)d_in[10];
    const float* ln_g  = (const float*)d_in[11];
    const float* ln_b  = (const float*)d_in[12];
    const float* t_w1  = (const float*)d_in[13];
    const float* t_b1  = (const float*)d_in[14];
    const float* t_g1  = (const float*)d_in[15];
    const float* t_bb1 = (const float*)d_in[16];
    const float* t_w2  = (const float*)d_in[17];
    const float* t_b2  = (const float*)d_in[18];
    const float* t_g2  = (const float*)d_in[19];
    const float* t_bb2 = (const float*)d_in[20];
    const float* t_w3  = (const float*)d_in[21];
    const float* t_b3  = (const float*)d_in[22];
    const float* t_g3  = (const float*)d_in[23];
    const float* t_bb3 = (const float*)d_in[24];
    const float* t_w4  = (const float*)d_in[25];
    const float* t_b4  = (const float*)d_in[26];

    char* ws = (char*)d_ws;
    float* wsM     = (float*)(ws);               // 400*4096 f32 = 6,553,600 B
    float* wsW     = (float*)(ws + 6553600);     // 400*4096 f32 = 6,553,600 B
    float* ubs_acc = (float*)(ws + 13107200);    // 256*8*64 f32 =   524,288 B

    hipMemsetAsync(ubs_acc, 0, B_ * F_ * E_ * sizeof(float), stream);

    precomp_kernel<<<L_ * H_, 256, 0, stream>>>(q_w, k_w, v_w, lin_w, wsM, wsW);

    attn_kernel<<<(L_ / LC_) * B_, 256, 0, stream>>>(
        ubs_feature, item_tables, wsM, wsW, lin_b, ln_g, ln_b, ubs_acc);

    tower_kernel<<<B_, 256, 0, stream>>>(
        ubs_acc, target_ad, profile_feature, context, item_tables, profile_tables,
        t_w1, t_b1, t_g1, t_bb1, t_w2, t_b2, t_g2, t_bb2,
        t_w3, t_b3, t_g3, t_bb3, t_w4, t_b4, (float*)d_out);
}

// Round 3
// 459.470 us; speedup vs baseline: 1.3827x; 1.3827x over previous
//
#include <hip/hip_runtime.h>
#include <hip/hip_bf16.h>

#define B_ 256
#define L_ 100
#define F_ 8
#define P_ 4
#define E_ 64
#define H_ 4
#define D_ 64
#define C_ 32
#define V_ 10000
#define TOWER_IN_ 1312
#define LN_EPS 0.001f
#define LCH_ 4    // l's per attention block
#define NCH_ 25   // number of l-chunks

typedef __attribute__((ext_vector_type(8))) short bf8v;   // 8 bf16 (4 VGPRs)
typedef __attribute__((ext_vector_type(4))) float f4v;    // 4 f32 acc

__device__ __forceinline__ unsigned short f2bf(float x) {
    __hip_bfloat16 h = __float2bfloat16(x);
    return __builtin_bit_cast(unsigned short, h);
}
__device__ __forceinline__ float bflo(unsigned u) { return __uint_as_float(u << 16); }
__device__ __forceinline__ float bfhi(unsigned u) { return __uint_as_float(u & 0xffff0000u); }
__device__ __forceinline__ void unp8(uint4 u, float* v) {
    v[0]=bflo(u.x); v[1]=bfhi(u.x); v[2]=bflo(u.y); v[3]=bfhi(u.y);
    v[4]=bflo(u.z); v[5]=bfhi(u.z); v[6]=bflo(u.w); v[7]=bfhi(u.w);
}

// ---------------------------------------------------------------------------
// Kernel P: precompute MT[l,h][o][e] = (Qh Kh^T)^T and WT[l,h][o][e] = (Vh Lh)^T
// in bf16.  grid = 400 blocks, 256 threads.
// ---------------------------------------------------------------------------
__global__ __launch_bounds__(256) void precomp_kernel(
    const float* __restrict__ q_w, const float* __restrict__ k_w,
    const float* __restrict__ v_w, const float* __restrict__ lin_w,
    unsigned short* __restrict__ wsMT, unsigned short* __restrict__ wsWT)
{
    __shared__ float sA[64][65];
    __shared__ float sB[64][65];
    const int t = threadIdx.x;
    const int l = blockIdx.x >> 2;
    const int h = blockIdx.x & 3;
    const size_t obase = (size_t)(l * 4 + h) * 4096;

    // phase 1: MT[o][e] = sum_d Q[e][d] * K[o][d]
    for (int i = 0; i < 16; ++i) {
        int idx = t + i * 256;
        int e = idx >> 6, d = idx & 63;
        sA[e][d] = q_w[(l * 64 + e) * 256 + h * 64 + d];
        sB[e][d] = k_w[(l * 64 + e) * 256 + h * 64 + d];
    }
    __syncthreads();
    for (int i = 0; i < 16; ++i) {
        int idx = t + i * 256;
        int o = idx >> 6, e = idx & 63;
        float s = 0.f;
        #pragma unroll 8
        for (int d = 0; d < 64; ++d) s += sA[e][d] * sB[o][d];
        wsMT[obase + idx] = f2bf(s);
    }
    __syncthreads();

    // phase 2: WT[o][e] = sum_d V[e][d] * Lh[d][o]
    for (int i = 0; i < 16; ++i) {
        int idx = t + i * 256;
        int dd = idx >> 6, oo = idx & 63;
        sB[dd][oo] = lin_w[l * 16384 + (h * 64 + dd) * 64 + oo];
    }
    for (int i = 0; i < 16; ++i) {
        int idx = t + i * 256;
        int e = idx >> 6, d = idx & 63;
        sA[e][d] = v_w[(l * 64 + e) * 256 + h * 64 + d];
    }
    __syncthreads();
    for (int i = 0; i < 16; ++i) {
        int idx = t + i * 256;
        int o = idx >> 6, e = idx & 63;
        float s = 0.f;
        #pragma unroll 8
        for (int d = 0; d < 64; ++d) s += sA[e][d] * sB[d][o];
        wsWT[obase + idx] = f2bf(s);
    }
}

// ---------------------------------------------------------------------------
// Kernel W: transpose tower weights to bf16 [n][k].  grid = 1952, 256 thr.
// ---------------------------------------------------------------------------
__global__ __launch_bounds__(256) void prep_kernel(
    const float* __restrict__ w1, const float* __restrict__ w2,
    const float* __restrict__ w3,
    unsigned short* __restrict__ Wt1, unsigned short* __restrict__ Wt2,
    unsigned short* __restrict__ Wt3)
{
    __shared__ float tile[32][33];
    int bx = blockIdx.x;
    const float* src; unsigned short* dst; int K, N, tk, tn;
    if (bx < 1312)      { src = w1; dst = Wt1; K = 1312; N = 1024; tk = bx / 32;  tn = bx % 32; }
    else if (bx < 1824) { int i = bx - 1312; src = w2; dst = Wt2; K = 1024; N = 512; tk = i / 16; tn = i % 16; }
    else                { int i = bx - 1824; src = w3; dst = Wt3; K = 512;  N = 256; tk = i / 8;  tn = i % 8; }
    const int k0 = tk * 32, n0 = tn * 32;
    const int rr = threadIdx.x >> 5, cc = threadIdx.x & 31;
    #pragma unroll
    for (int i = 0; i < 4; ++i) {
        int r = rr * 4 + i;
        tile[r][cc] = src[(size_t)(k0 + r) * N + n0 + cc];
    }
    __syncthreads();
    #pragma unroll
    for (int i = 0; i < 4; ++i) {
        int r = rr * 4 + i;
        dst[(size_t)(n0 + r) * K + k0 + cc] = f2bf(tile[cc][r]);
    }
}

// ---------------------------------------------------------------------------
// Kernel A: fused attention.  grid = NCH_*16 blocks, 512 threads (8 waves).
// Block = (l-chunk of LCH_, 16 b's).  MFMA for T=UE@M, Z=UE@W; VALU rest.
// ---------------------------------------------------------------------------
__global__ __launch_bounds__(512) void attn_kernel(
    const int* __restrict__ ubs_feature, const float* __restrict__ item_tables,
    const unsigned short* __restrict__ wsMT, const unsigned short* __restrict__ wsWT,
    const float* __restrict__ lin_b, const float* __restrict__ ln_g,
    const float* __restrict__ ln_b, float* __restrict__ parts)
{
    __shared__ unsigned short sUE[128][72];
    __shared__ unsigned short sT[128][72];
    __shared__ unsigned short sZ[128][72];
    __shared__ float sAttw[128][8];
    __shared__ float sLng[64], sLnb[64], sLinb[64];

    const int t = threadIdx.x;
    const int c = blockIdx.x >> 4;        // l-chunk
    const int bch = blockIdx.x & 15;
    const int b0 = bch * 16;
    const int wv = t >> 6;
    const int lane = t & 63;
    const int quad = lane >> 4;
    const int cl = lane & 15;

    const int p   = t >> 2;               // 0..127 : row = b_local*8 + f
    const int seg = t & 3;
    const int bl  = p >> 3;
    const int fq  = p & 7;
    const int e0  = seg * 16;

    if (t < 64) { sLng[t] = ln_g[t]; sLnb[t] = ln_b[t]; }

    float lnacc[16];
    #pragma unroll
    for (int i = 0; i < 16; ++i) lnacc[i] = 0.f;

    for (int li = 0; li < LCH_; ++li) {
        const int l = c * LCH_ + li;
        if (t >= 64 && t < 128) sLinb[t - 64] = lin_b[l * 64 + (t - 64)];

        // gather UE rows (f32 -> bf16)
        {
            const int bg = b0 + bl;
            const int vidx = ubs_feature[(bg * L_ + l) * F_ + fq];
            const float* src = item_tables + ((size_t)fq * V_ + vidx) * 64 + e0;
            #pragma unroll
            for (int j = 0; j < 8; ++j) {
                float x0 = src[2 * j], x1 = src[2 * j + 1];
                unsigned u = (unsigned)f2bf(x0) | ((unsigned)f2bf(x1) << 16);
                *(unsigned*)&sUE[p][e0 + 2 * j] = u;
            }
        }
        __syncthreads();

        float pvacc[16];
        #pragma unroll
        for (int i = 0; i < 16; ++i) pvacc[i] = 0.f;

        for (int h = 0; h < 4; ++h) {
            // ---- MFMA: waves 0-3 -> T rows, waves 4-7 -> Z rows ----
            {
                const int role = wv >> 2;
                const int wr = wv & 3;
                const unsigned short* Bsrc = (role == 0 ? wsMT : wsWT) + (size_t)(l * 4 + h) * 4096;
                unsigned short (*dst)[72] = (role == 0) ? sT : sZ;
                bf8v bfrag[4][2];
                #pragma unroll
                for (int nt = 0; nt < 4; ++nt)
                    #pragma unroll
                    for (int kk = 0; kk < 2; ++kk)
                        bfrag[nt][kk] = *(const bf8v*)(Bsrc + (nt * 16 + cl) * 64 + kk * 32 + quad * 8);
                #pragma unroll
                for (int mi = 0; mi < 2; ++mi) {
                    const int row0 = wr * 32 + mi * 16;
                    bf8v a0 = *(const bf8v*)&sUE[row0 + cl][0 + quad * 8];
                    bf8v a1 = *(const bf8v*)&sUE[row0 + cl][32 + quad * 8];
                    #pragma unroll
                    for (int nt = 0; nt < 4; ++nt) {
                        f4v acc = {0.f, 0.f, 0.f, 0.f};
                        acc = __builtin_amdgcn_mfma_f32_16x16x32_bf16(a0, bfrag[nt][0], acc, 0, 0, 0);
                        acc = __builtin_amdgcn_mfma_f32_16x16x32_bf16(a1, bfrag[nt][1], acc, 0, 0, 0);
                        #pragma unroll
                        for (int j = 0; j < 4; ++j)
                            dst[row0 + quad * 4 + j][nt * 16 + cl] = f2bf(acc[j]);
                    }
                }
            }
            __syncthreads();

            // ---- scores + softmax ----
            {
                float sc[8];
                #pragma unroll
                for (int g = 0; g < 8; ++g) sc[g] = 0.f;
                #pragma unroll
                for (int ch = 0; ch < 2; ++ch) {
                    float tv[8];
                    unp8(*(const uint4*)&sT[p][e0 + ch * 8], tv);
                    #pragma unroll
                    for (int g = 0; g < 8; ++g) {
                        float uv[8];
                        unp8(*(const uint4*)&sUE[bl * 8 + g][e0 + ch * 8], uv);
                        #pragma unroll
                        for (int j = 0; j < 8; ++j) sc[g] += tv[j] * uv[j];
                    }
                }
                #pragma unroll
                for (int g = 0; g < 8; ++g) {
                    float v = sc[g];
                    v += __shfl_xor(v, 1, 4);
                    v += __shfl_xor(v, 2, 4);
                    sc[g] = v * 0.125f;
                }
                float mx = sc[0];
                #pragma unroll
                for (int g = 1; g < 8; ++g) mx = fmaxf(mx, sc[g]);
                float ex[8], sum = 0.f;
                #pragma unroll
                for (int g = 0; g < 8; ++g) { ex[g] = __expf(sc[g] - mx); sum += ex[g]; }
                float inv = 1.f / sum;
                if (seg == 0) {
                    #pragma unroll
                    for (int g = 0; g < 8; ++g) sAttw[p][g] = ex[g] * inv;
                }
            }
            __syncthreads();

            // ---- PV: pvacc += attw @ Z ----
            {
                float aw[8];
                #pragma unroll
                for (int g = 0; g < 8; ++g) aw[g] = sAttw[p][g];
                #pragma unroll
                for (int g = 0; g < 8; ++g) {
                    float zv[16];
                    unp8(*(const uint4*)&sZ[bl * 8 + g][e0], zv);
                    unp8(*(const uint4*)&sZ[bl * 8 + g][e0 + 8], zv + 8);
                    float a = aw[g];
                    #pragma unroll
                    for (int i = 0; i < 16; ++i) pvacc[i] += a * zv[i];
                }
            }
            __syncthreads();
        }

        // ---- +lin_b, LayerNorm over e (4 seg lanes), accumulate over l ----
        {
            float x[16]; float s = 0.f;
            #pragma unroll
            for (int i = 0; i < 16; ++i) { x[i] = pvacc[i] + sLinb[e0 + i]; s += x[i]; }
            s += __shfl_xor(s, 1, 4);
            s += __shfl_xor(s, 2, 4);
            float mean = s * (1.f / 64.f);
            float q = 0.f;
            #pragma unroll
            for (int i = 0; i < 16; ++i) { float d = x[i] - mean; q += d * d; }
            q += __shfl_xor(q, 1, 4);
            q += __shfl_xor(q, 2, 4);
            float rst = rsqrtf(q * (1.f / 64.f) + LN_EPS);
            #pragma unroll
            for (int i = 0; i < 16; ++i)
                lnacc[i] += (x[i] - mean) * rst * sLng[e0 + i] + sLnb[e0 + i];
        }
        __syncthreads();
    }

    float* dst = parts + ((size_t)(c * 256 + b0 + bl)) * 512 + fq * 64 + e0;
    #pragma unroll
    for (int i = 0; i < 4; ++i)
        *(float4*)(dst + i * 4) = *(float4*)&lnacc[i * 4];
}

// ---------------------------------------------------------------------------
// Kernel R: reduce parts over l-chunks -> ubs = relu(sum/100).  grid = 256.
// ---------------------------------------------------------------------------
__global__ __launch_bounds__(256) void reduce_kernel(
    const float* __restrict__ parts, float* __restrict__ ubsX)
{
    const int b = blockIdx.x, t = threadIdx.x;
    float s0 = 0.f, s1 = 0.f;
    for (int ch = 0; ch < NCH_; ++ch) {
        const float2 v = *(const float2*)(parts + ((size_t)(ch * 256 + b)) * 512 + t * 2);
        s0 += v.x; s1 += v.y;
    }
    ubsX[b * 512 + t * 2]     = fmaxf(s0 * 0.01f, 0.f);
    ubsX[b * 512 + t * 2 + 1] = fmaxf(s1 * 0.01f, 0.f);
}

// ---------------------------------------------------------------------------
// Kernel T: fused MFMA tower.  grid = 16 blocks x 512 thr, 16 b per block.
// ---------------------------------------------------------------------------
__global__ __launch_bounds__(512) void tower_kernel(
    const float* __restrict__ ubsX,
    const int* __restrict__ target_ad, const int* __restrict__ profile_feature,
    const float* __restrict__ context,
    const float* __restrict__ item_tables, const float* __restrict__ profile_tables,
    const unsigned short* __restrict__ Wt1, const float* __restrict__ b1,
    const float* __restrict__ g1, const float* __restrict__ bb1,
    const unsigned short* __restrict__ Wt2, const float* __restrict__ b2,
    const float* __restrict__ g2, const float* __restrict__ bb2,
    const unsigned short* __restrict__ Wt3, const float* __restrict__ b3,
    const float* __restrict__ g3, const float* __restrict__ bb3,
    const float* __restrict__ w4, const float* __restrict__ b4,
    unsigned short* __restrict__ Xb, float* __restrict__ out)
{
    __shared__ unsigned short sH1[16][1032];
    __shared__ unsigned short sH2[16][520];
    __shared__ float sRedS[16][8], sRedQ[16][8], sL4[16][8];

    const int t = threadIdx.x, b0 = blockIdx.x * 16;
    const int wv = t >> 6, lane = t & 63, quad = lane >> 4, cl = lane & 15;
    unsigned short* X = Xb + (size_t)blockIdx.x * 16 * 1312;

    // stage X (bf16) to workspace
    {
        const int r = t >> 5, c0 = t & 31;
        const int bg = b0 + r;
        for (int cc = c0; cc < 1312; cc += 32) {
            float v;
            if (cc < 512) v = ubsX[bg * 512 + cc];
            else if (cc < 1024) { int j = cc - 512, f = j >> 6, e = j & 63;
                v = item_tables[((size_t)f * V_ + target_ad[bg * 8 + f]) * 64 + e]; }
            else if (cc < 1280) { int j = cc - 1024, pp = j >> 6, e = j & 63;
                v = profile_tables[((size_t)pp * V_ + profile_feature[bg * 4 + pp]) * 64 + e]; }
            else v = context[bg * 32 + (cc - 1280)];
            X[r * 1312 + cc] = f2bf(v);
        }
    }
    __syncthreads();

    // ---- layer 1: 1312 -> 1024, +b, LN, ReLU -> sH1 ----
    {
        f4v acc[8];
        #pragma unroll
        for (int nt = 0; nt < 8; ++nt) acc[nt] = {0.f, 0.f, 0.f, 0.f};
        const int nbase = wv * 128;
        for (int kk = 0; kk < 41; ++kk) {
            const int k0 = kk * 32;
            bf8v a = *(const bf8v*)(X + cl * 1312 + k0 + quad * 8);
            #pragma unroll
            for (int nt = 0; nt < 8; ++nt) {
                bf8v b = *(const bf8v*)(Wt1 + (size_t)(nbase + nt * 16 + cl) * 1312 + k0 + quad * 8);
                acc[nt] = __builtin_amdgcn_mfma_f32_16x16x32_bf16(a, b, acc[nt], 0, 0, 0);
            }
        }
        float bsum[4] = {0,0,0,0}, bsq[4] = {0,0,0,0};
        #pragma unroll
        for (int nt = 0; nt < 8; ++nt) {
            float bv = b1[nbase + nt * 16 + cl];
            #pragma unroll
            for (int j = 0; j < 4; ++j) {
                float x = acc[nt][j] + bv; acc[nt][j] = x;
                bsum[j] += x; bsq[j] += x * x;
            }
        }
        #pragma unroll
        for (int j = 0; j < 4; ++j) {
            #pragma unroll
            for (int m = 1; m < 16; m <<= 1) {
                bsum[j] += __shfl_xor(bsum[j], m, 16);
                bsq[j]  += __shfl_xor(bsq[j],  m, 16);
            }
        }
        if (cl == 0) {
            #pragma unroll
            for (int j = 0; j < 4; ++j) { sRedS[quad * 4 + j][wv] = bsum[j]; sRedQ[quad * 4 + j][wv] = bsq[j]; }
        }
        __syncthreads();
        float mean[4], rst[4];
        #pragma unroll
        for (int j = 0; j < 4; ++j) {
            int row = quad * 4 + j; float s = 0.f, q = 0.f;
            #pragma unroll
            for (int w = 0; w < 8; ++w) { s += sRedS[row][w]; q += sRedQ[row][w]; }
            float m_ = s * (1.f / 1024.f);
            float v_ = q * (1.f / 1024.f) - m_ * m_;
            mean[j] = m_; rst[j] = rsqrtf(fmaxf(v_, 0.f) + LN_EPS);
        }
        #pragma unroll
        for (int nt = 0; nt < 8; ++nt) {
            int col = nbase + nt * 16 + cl;
            float gv = g1[col], bbv = bb1[col];
            #pragma unroll
            for (int j = 0; j < 4; ++j) {
                float y = (acc[nt][j] - mean[j]) * rst[j] * gv + bbv;
                sH1[quad * 4 + j][col] = f2bf(fmaxf(y, 0.f));
            }
        }
    }
    __syncthreads();

    // ---- layer 2: 1024 -> 512 -> sH2 ----
    {
        f4v acc[4];
        #pragma unroll
        for (int nt = 0; nt < 4; ++nt) acc[nt] = {0.f, 0.f, 0.f, 0.f};
        const int nbase = wv * 64;
        for (int kk = 0; kk < 32; ++kk) {
            const int k0 = kk * 32;
            bf8v a = *(const bf8v*)&sH1[cl][k0 + quad * 8];
            #pragma unroll
            for (int nt = 0; nt < 4; ++nt) {
                bf8v b = *(const bf8v*)(Wt2 + (size_t)(nbase + nt * 16 + cl) * 1024 + k0 + quad * 8);
                acc[nt] = __builtin_amdgcn_mfma_f32_16x16x32_bf16(a, b, acc[nt], 0, 0, 0);
            }
        }
        float bsum[4] = {0,0,0,0}, bsq[4] = {0,0,0,0};
        #pragma unroll
        for (int nt = 0; nt < 4; ++nt) {
            float bv = b2[nbase + nt * 16 + cl];
            #pragma unroll
            for (int j = 0; j < 4; ++j) {
                float x = acc[nt][j] + bv; acc[nt][j] = x;
                bsum[j] += x; bsq[j] += x * x;
            }
        }
        #pragma unroll
        for (int j = 0; j < 4; ++j) {
            #pragma unroll
            for (int m = 1; m < 16; m <<= 1) {
                bsum[j] += __shfl_xor(bsum[j], m, 16);
                bsq[j]  += __shfl_xor(bsq[j],  m, 16);
            }
        }
        if (cl == 0) {
            #pragma unroll
            for (int j = 0; j < 4; ++j) { sRedS[quad * 4 + j][wv] = bsum[j]; sRedQ[quad * 4 + j][wv] = bsq[j]; }
        }
        __syncthreads();
        float mean[4], rst[4];
        #pragma unroll
        for (int j = 0; j < 4; ++j) {
            int row = quad * 4 + j; float s = 0.f, q = 0.f;
            #pragma unroll
            for (int w = 0; w < 8; ++w) { s += sRedS[row][w]; q += sRedQ[row][w]; }
            float m_ = s * (1.f / 512.f);
            float v_ = q * (1.f / 512.f) - m_ * m_;
            mean[j] = m_; rst[j] = rsqrtf(fmaxf(v_, 0.f) + LN_EPS);
        }
        #pragma unroll
        for (int nt = 0; nt < 4; ++nt) {
            int col = nbase + nt * 16 + cl;
            float gv = g2[col], bbv = bb2[col];
            #pragma unroll
            for (int j = 0; j < 4; ++j) {
                float y = (acc[nt][j] - mean[j]) * rst[j] * gv + bbv;
                sH2[quad * 4 + j][col] = f2bf(fmaxf(y, 0.f));
            }
        }
    }
    __syncthreads();

    // ---- layer 3: 512 -> 256, LN, ReLU (regs) + layer 4 dot ----
    {
        f4v acc[2];
        #pragma unroll
        for (int nt = 0; nt < 2; ++nt) acc[nt] = {0.f, 0.f, 0.f, 0.f};
        const int nbase = wv * 32;
        for (int kk = 0; kk < 16; ++kk) {
            const int k0 = kk * 32;
            bf8v a = *(const bf8v*)&sH2[cl][k0 + quad * 8];
            #pragma unroll
            for (int nt = 0; nt < 2; ++nt) {
                bf8v b = *(const bf8v*)(Wt3 + (size_t)(nbase + nt * 16 + cl) * 512 + k0 + quad * 8);
                acc[nt] = __builtin_amdgcn_mfma_f32_16x16x32_bf16(a, b, acc[nt], 0, 0, 0);
            }
        }
        float bsum[4] = {0,0,0,0}, bsq[4] = {0,0,0,0};
        #pragma unroll
        for (int nt = 0; nt < 2; ++nt) {
            float bv = b3[nbase + nt * 16 + cl];
            #pragma unroll
            for (int j = 0; j < 4; ++j) {
                float x = acc[nt][j] + bv; acc[nt][j] = x;
                bsum[j] += x; bsq[j] += x * x;
            }
        }
        #pragma unroll
        for (int j = 0; j < 4; ++j) {
            #pragma unroll
            for (int m = 1; m < 16; m <<= 1) {
                bsum[j] += __shfl_xor(bsum[j], m, 16);
                bsq[j]  += __shfl_xor(bsq[j],  m, 16);
            }
        }
        if (cl == 0) {
            #pragma unroll
            for (int j = 0; j < 4; ++j) { sRedS[quad * 4 + j][wv] = bsum[j]; sRedQ[quad * 4 + j][wv] = bsq[j]; }
        }
        __syncthreads();
        float part[4];
        #pragma unroll
        for (int j = 0; j < 4; ++j) {
            int row = quad * 4 + j; float s = 0.f, q = 0.f;
            #pragma unroll
            for (int w = 0; w < 8; ++w) { s += sRedS[row][w]; q += sRedQ[row][w]; }
            float m_ = s * (1.f / 256.f);
            float v_ = q * (1.f / 256.f) - m_ * m_;
            float rst = rsqrtf(fmaxf(v_, 0.f) + LN_EPS);
            float pp = 0.f;
            #pragma unroll
            for (int nt = 0; nt < 2; ++nt) {
                int col = nbase + nt * 16 + cl;
                float y = (acc[nt][j] - m_) * rst * g3[col] + bb3[col];
                pp += fmaxf(y, 0.f) * w4[col];
            }
            part[j] = pp;
        }
        #pragma unroll
        for (int j = 0; j < 4; ++j) {
            #pragma unroll
            for (int m = 1; m < 16; m <<= 1) part[j] += __shfl_xor(part[j], m, 16);
        }
        if (cl == 0) {
            #pragma unroll
            for (int j = 0; j < 4; ++j) sL4[quad * 4 + j][wv] = part[j];
        }
        __syncthreads();
        if (t < 16) {
            float y = b4[0];
            #pragma unroll
            for (int w = 0; w < 8; ++w) y += sL4[t][w];
            out[b0 + t] = 1.f / (1.f + expf(-y));
        }
    }
}

// ---------------------------------------------------------------------------
extern "C" void kernel_launch(void* const* d_in, const int* in_sizes, int n_in,
                              void* d_out, int out_size, void* d_ws, size_t ws_size,
                              hipStream_t stream)
{
    (void)in_sizes; (void)n_in; (void)out_size; (void)ws_size;
    const int*   target_ad       = (const int*)d_in[0];
    const int*   ubs_feature     = (const int*)d_in[1];
    const int*   profile_feature = (const int*)d_in[2];
    const float* context         = (const float*)d_in[3];
    const float* item_tables     = (const float*)d_in[4];
    const float* profile_tables  = (const float*)d_in[5];
    const float* q_w   = (const float*)d_in[6];
    const float* k_w   = (const float*)d_in[7];
    const float* v_w   = (const float*)d_in[8];
    const float* lin_w = (const float*)d_in[9];
    const float* lin_b = (const float*)d_in[10];
    const float* ln_g  = (const float*)d_in[11];
    const float* ln_b  = (const float*)d_in[12];
    const float* t_w1  = (const float*)d_in[13];
    const float* t_b1  = (const float*)d_in[14];
    const float* t_g1  = (const float*)d_in[15];
    const float* t_bb1 = (const float*)d_in[16];
    const float* t_w2  = (const float*)d_in[17];
    const float* t_b2  = (const float*)d_in[18];
    const float* t_g2  = (const float*)d_in[19];
    const float* t_bb2 = (const float*)d_in[20];
    const float* t_w3  = (const float*)d_in[21];
    const float* t_b3  = (const float*)d_in[22];
    const float* t_g3  = (const float*)d_in[23];
    const float* t_bb3 = (const float*)d_in[24];
    const float* t_w4  = (const float*)d_in[25];
    const float* t_b4  = (const float*)d_in[26];

    char* ws = (char*)d_ws;
    unsigned short* wsMT = (unsigned short*)(ws);             // 3,276,800 B
    unsigned short* wsWT = (unsigned short*)(ws + 3276800);   // 3,276,800 B
    float* parts = (float*)(ws + 6553600);                    // 25*256*512*4 = 13,107,200 B
    float* ubsX  = (float*)(ws + 19660800);                   //   524,288 B
    unsigned short* Wt1 = (unsigned short*)(ws + 20185088);   // 2,686,976 B
    unsigned short* Wt2 = (unsigned short*)(ws + 22872064);   // 1,048,576 B
    unsigned short* Wt3 = (unsigned short*)(ws + 23920640);   //   262,144 B
    unsigned short* Xb  = (unsigned short*)(ws + 24182784);   //   671,744 B  (end 24,854,528)

    prep_kernel<<<1952, 256, 0, stream>>>(t_w1, t_w2, t_w3, Wt1, Wt2, Wt3);
    precomp_kernel<<<L_ * H_, 256, 0, stream>>>(q_w, k_w, v_w, lin_w, wsMT, wsWT);
    attn_kernel<<<NCH_ * 16, 512, 0, stream>>>(ubs_feature, item_tables, wsMT, wsWT,
                                               lin_b, ln_g, ln_b, parts);
    reduce_kernel<<<B_, 256, 0, stream>>>(parts, ubsX);
    tower_kernel<<<16, 512, 0, stream>>>(ubsX, target_ad, profile_feature, context,
        item_tables, profile_tables,
        Wt1, t_b1, t_g1, t_bb1, Wt2, t_b2, t_g2, t_bb2,
        Wt3, t_b3, t_g3, t_bb3, t_w4, t_b4, Xb, (float*)d_out);
}

// Round 4
// 422.207 us; speedup vs baseline: 1.5047x; 1.0883x over previous
//
#include <hip/hip_runtime.h>
#include <hip/hip_bf16.h>

#define B_ 256
#define L_ 100
#define F_ 8
#define P_ 4
#define E_ 64
#define H_ 4
#define D_ 64
#define C_ 32
#define V_ 10000
#define TOWER_IN_ 1312
#define LN_EPS 0.001f
#define LCH_ 2    // l's per attention block
#define NCH_ 50   // number of l-chunks

typedef __attribute__((ext_vector_type(8))) short bf8v;   // 8 bf16 (4 VGPRs)
typedef __attribute__((ext_vector_type(4))) float f4v;    // 4 f32 acc

__device__ __forceinline__ unsigned short f2bf(float x) {
    __hip_bfloat16 h = __float2bfloat16(x);
    return __builtin_bit_cast(unsigned short, h);
}
__device__ __forceinline__ float bflo(unsigned u) { return __uint_as_float(u << 16); }
__device__ __forceinline__ float bfhi(unsigned u) { return __uint_as_float(u & 0xffff0000u); }
__device__ __forceinline__ void unp8(uint4 u, float* v) {
    v[0]=bflo(u.x); v[1]=bfhi(u.x); v[2]=bflo(u.y); v[3]=bfhi(u.y);
    v[4]=bflo(u.z); v[5]=bfhi(u.z); v[6]=bflo(u.w); v[7]=bfhi(u.w);
}

// ---------------------------------------------------------------------------
// Kernel P: precompute MT[l,h][o][e] = (Qh Kh^T)^T and WT[l,h][o][e] = (Vh Lh)^T
// in bf16.  grid = 400 blocks, 256 threads.   (verified R3)
// ---------------------------------------------------------------------------
__global__ __launch_bounds__(256) void precomp_kernel(
    const float* __restrict__ q_w, const float* __restrict__ k_w,
    const float* __restrict__ v_w, const float* __restrict__ lin_w,
    unsigned short* __restrict__ wsMT, unsigned short* __restrict__ wsWT)
{
    __shared__ float sA[64][65];
    __shared__ float sB[64][65];
    const int t = threadIdx.x;
    const int l = blockIdx.x >> 2;
    const int h = blockIdx.x & 3;
    const size_t obase = (size_t)(l * 4 + h) * 4096;

    for (int i = 0; i < 16; ++i) {
        int idx = t + i * 256;
        int e = idx >> 6, d = idx & 63;
        sA[e][d] = q_w[(l * 64 + e) * 256 + h * 64 + d];
        sB[e][d] = k_w[(l * 64 + e) * 256 + h * 64 + d];
    }
    __syncthreads();
    for (int i = 0; i < 16; ++i) {
        int idx = t + i * 256;
        int o = idx >> 6, e = idx & 63;
        float s = 0.f;
        #pragma unroll 8
        for (int d = 0; d < 64; ++d) s += sA[e][d] * sB[o][d];
        wsMT[obase + idx] = f2bf(s);
    }
    __syncthreads();

    for (int i = 0; i < 16; ++i) {
        int idx = t + i * 256;
        int dd = idx >> 6, oo = idx & 63;
        sB[dd][oo] = lin_w[l * 16384 + (h * 64 + dd) * 64 + oo];
    }
    for (int i = 0; i < 16; ++i) {
        int idx = t + i * 256;
        int e = idx >> 6, d = idx & 63;
        sA[e][d] = v_w[(l * 64 + e) * 256 + h * 64 + d];
    }
    __syncthreads();
    for (int i = 0; i < 16; ++i) {
        int idx = t + i * 256;
        int o = idx >> 6, e = idx & 63;
        float s = 0.f;
        #pragma unroll 8
        for (int d = 0; d < 64; ++d) s += sA[e][d] * sB[d][o];
        wsWT[obase + idx] = f2bf(s);
    }
}

// ---------------------------------------------------------------------------
// Kernel W: transpose tower weights to bf16 [n][k].  grid = 1952, 256 thr.
// ---------------------------------------------------------------------------
__global__ __launch_bounds__(256) void prep_kernel(
    const float* __restrict__ w1, const float* __restrict__ w2,
    const float* __restrict__ w3,
    unsigned short* __restrict__ Wt1, unsigned short* __restrict__ Wt2,
    unsigned short* __restrict__ Wt3)
{
    __shared__ float tile[32][33];
    int bx = blockIdx.x;
    const float* src; unsigned short* dst; int K, N, tk, tn;
    if (bx < 1312)      { src = w1; dst = Wt1; K = 1312; N = 1024; tk = bx / 32;  tn = bx % 32; }
    else if (bx < 1824) { int i = bx - 1312; src = w2; dst = Wt2; K = 1024; N = 512; tk = i / 16; tn = i % 16; }
    else                { int i = bx - 1824; src = w3; dst = Wt3; K = 512;  N = 256; tk = i / 8;  tn = i % 8; }
    const int k0 = tk * 32, n0 = tn * 32;
    const int rr = threadIdx.x >> 5, cc = threadIdx.x & 31;
    #pragma unroll
    for (int i = 0; i < 4; ++i) {
        int r = rr * 4 + i;
        tile[r][cc] = src[(size_t)(k0 + r) * N + n0 + cc];
    }
    __syncthreads();
    #pragma unroll
    for (int i = 0; i < 4; ++i) {
        int r = rr * 4 + i;
        dst[(size_t)(n0 + r) * K + k0 + cc] = f2bf(tile[cc][r]);
    }
}

// ---------------------------------------------------------------------------
// Kernel A: fused attention.  grid = NCH_*16 blocks, 512 threads (8 waves).
// Per l: phase A MFMA T=UE@M (2 heads), VALU scores/softmax, G=attw@UE in
// place of T, phase B MFMA out += G@W (register acc), LN at end of l.
// ---------------------------------------------------------------------------
__global__ __launch_bounds__(512) void attn_kernel(
    const int* __restrict__ ubs_feature, const float* __restrict__ item_tables,
    const unsigned short* __restrict__ wsMT, const unsigned short* __restrict__ wsWT,
    const float* __restrict__ lin_b, const float* __restrict__ ln_g,
    const float* __restrict__ ln_b, float* __restrict__ parts)
{
    __shared__ unsigned short sUE[128][72];    // rows = bl*8+f, cols = e
    __shared__ unsigned short sT[128][136];    // T then G, 2 heads (128 cols)
    __shared__ float sLng[64], sLnb[64], sLinb[64];

    const int t = threadIdx.x;
    const int c = blockIdx.x >> 4;            // l-chunk
    const int b0 = (blockIdx.x & 15) * 16;
    const int wv = t >> 6, lane = t & 63, quad = lane >> 4, cl = lane & 15;
    const int p = t >> 2, seg = t & 3;        // p: row 0..127, seg: e-quarter
    const int bl = p >> 3, fq = p & 7;
    const int e0 = seg * 16;

    if (t < 64) { sLng[t] = ln_g[t]; sLnb[t] = ln_b[t]; }

    float lnacc[16];                           // [nt*4+j]
    #pragma unroll
    for (int i = 0; i < 16; ++i) lnacc[i] = 0.f;

    for (int li = 0; li < LCH_; ++li) {
        const int l = c * LCH_ + li;
        if (t >= 64 && t < 128) sLinb[t - 64] = lin_b[l * 64 + (t - 64)];

        // ---- gather UE rows (f32 -> bf16) ----
        {
            const int bg = b0 + bl;
            const int vidx = ubs_feature[(bg * L_ + l) * F_ + fq];
            const float* src = item_tables + ((size_t)fq * V_ + vidx) * 64 + e0;
            #pragma unroll
            for (int j = 0; j < 8; ++j) {
                float x0 = src[2 * j], x1 = src[2 * j + 1];
                unsigned u = (unsigned)f2bf(x0) | ((unsigned)f2bf(x1) << 16);
                *(unsigned*)&sUE[p][e0 + 2 * j] = u;
            }
        }
        __syncthreads();

        f4v accO[4];
        #pragma unroll
        for (int nt = 0; nt < 4; ++nt) accO[nt] = {0.f, 0.f, 0.f, 0.f};

        for (int half = 0; half < 2; ++half) {
            // ---- phase A: T(2 heads) = UE @ M ; wave wv -> n-tile wv ----
            {
                const int hl = wv >> 2;
                const int og = (wv & 3) * 16;
                const unsigned short* Msrc = wsMT + (size_t)(l * 4 + half * 2 + hl) * 4096;
                bf8v bf0 = *(const bf8v*)(Msrc + (og + cl) * 64 + quad * 8);
                bf8v bf1 = *(const bf8v*)(Msrc + (og + cl) * 64 + 32 + quad * 8);
                #pragma unroll
                for (int mt = 0; mt < 8; ++mt) {
                    bf8v a0 = *(const bf8v*)&sUE[mt * 16 + cl][quad * 8];
                    bf8v a1 = *(const bf8v*)&sUE[mt * 16 + cl][32 + quad * 8];
                    f4v acc = {0.f, 0.f, 0.f, 0.f};
                    acc = __builtin_amdgcn_mfma_f32_16x16x32_bf16(a0, bf0, acc, 0, 0, 0);
                    acc = __builtin_amdgcn_mfma_f32_16x16x32_bf16(a1, bf1, acc, 0, 0, 0);
                    #pragma unroll
                    for (int j = 0; j < 4; ++j)
                        sT[mt * 16 + quad * 4 + j][wv * 16 + cl] = f2bf(acc[j]);
                }
            }
            __syncthreads();

            // ---- scores + softmax + G (thread = (row p, e-quarter seg)) ----
            #pragma unroll
            for (int hl = 0; hl < 2; ++hl) {
                float tv[16];
                unp8(*(const uint4*)&sT[p][hl * 64 + e0], tv);
                unp8(*(const uint4*)&sT[p][hl * 64 + e0 + 8], tv + 8);
                float sc[8];
                #pragma unroll
                for (int g = 0; g < 8; ++g) {
                    float uv[16];
                    unp8(*(const uint4*)&sUE[bl * 8 + g][e0], uv);
                    unp8(*(const uint4*)&sUE[bl * 8 + g][e0 + 8], uv + 8);
                    float s = 0.f;
                    #pragma unroll
                    for (int i = 0; i < 16; ++i) s += tv[i] * uv[i];
                    sc[g] = s;
                }
                #pragma unroll
                for (int g = 0; g < 8; ++g) {
                    float v = sc[g];
                    v += __shfl_xor(v, 1, 4);
                    v += __shfl_xor(v, 2, 4);
                    sc[g] = v * 0.125f;
                }
                float mx = sc[0];
                #pragma unroll
                for (int g = 1; g < 8; ++g) mx = fmaxf(mx, sc[g]);
                float aw[8], sum = 0.f;
                #pragma unroll
                for (int g = 0; g < 8; ++g) { aw[g] = __expf(sc[g] - mx); sum += aw[g]; }
                float inv = 1.f / sum;
                // G[f][e-range of seg] = sum_g attw[g] * UE[g][e]
                float gv[16];
                #pragma unroll
                for (int i = 0; i < 16; ++i) gv[i] = 0.f;
                #pragma unroll
                for (int g = 0; g < 8; ++g) {
                    float uv[16];
                    unp8(*(const uint4*)&sUE[bl * 8 + g][e0], uv);
                    unp8(*(const uint4*)&sUE[bl * 8 + g][e0 + 8], uv + 8);
                    float a = aw[g] * inv;
                    #pragma unroll
                    for (int i = 0; i < 16; ++i) gv[i] += a * uv[i];
                }
                #pragma unroll
                for (int i = 0; i < 16; ++i)
                    sT[p][hl * 64 + e0 + i] = f2bf(gv[i]);   // overwrite own cells
            }
            __syncthreads();

            // ---- phase B: accO += G @ W (wave wv -> m-tile wv) ----
            #pragma unroll
            for (int hl = 0; hl < 2; ++hl) {
                const unsigned short* Wsrc = wsWT + (size_t)(l * 4 + half * 2 + hl) * 4096;
                bf8v a0 = *(const bf8v*)&sT[wv * 16 + cl][hl * 64 + quad * 8];
                bf8v a1 = *(const bf8v*)&sT[wv * 16 + cl][hl * 64 + 32 + quad * 8];
                #pragma unroll
                for (int nt = 0; nt < 4; ++nt) {
                    bf8v bb0 = *(const bf8v*)(Wsrc + (nt * 16 + cl) * 64 + quad * 8);
                    bf8v bb1 = *(const bf8v*)(Wsrc + (nt * 16 + cl) * 64 + 32 + quad * 8);
                    accO[nt] = __builtin_amdgcn_mfma_f32_16x16x32_bf16(a0, bb0, accO[nt], 0, 0, 0);
                    accO[nt] = __builtin_amdgcn_mfma_f32_16x16x32_bf16(a1, bb1, accO[nt], 0, 0, 0);
                }
            }
            __syncthreads();
        }

        // ---- + lin_b, LayerNorm per row over 64 cols, accumulate over l ----
        {
            float x[16];
            #pragma unroll
            for (int nt = 0; nt < 4; ++nt)
                #pragma unroll
                for (int j = 0; j < 4; ++j)
                    x[nt * 4 + j] = accO[nt][j] + sLinb[nt * 16 + cl];
            #pragma unroll
            for (int j = 0; j < 4; ++j) {
                float s = x[j] + x[4 + j] + x[8 + j] + x[12 + j];
                #pragma unroll
                for (int m = 1; m < 16; m <<= 1) s += __shfl_xor(s, m, 16);
                float mean = s * (1.f / 64.f);
                float q = 0.f;
                #pragma unroll
                for (int nt = 0; nt < 4; ++nt) { float d = x[nt * 4 + j] - mean; q += d * d; }
                #pragma unroll
                for (int m = 1; m < 16; m <<= 1) q += __shfl_xor(q, m, 16);
                float rst = rsqrtf(q * (1.f / 64.f) + LN_EPS);
                #pragma unroll
                for (int nt = 0; nt < 4; ++nt) {
                    int col = nt * 16 + cl;
                    lnacc[nt * 4 + j] += (x[nt * 4 + j] - mean) * rst * sLng[col] + sLnb[col];
                }
            }
        }
        __syncthreads();
    }

    // write parts: rows wv*16+quad*4+j, cols nt*16+cl
    #pragma unroll
    for (int j = 0; j < 4; ++j) {
        int row = wv * 16 + quad * 4 + j;
        int blr = row >> 3, fr = row & 7;
        float* dst = parts + ((size_t)(c * 256 + b0 + blr)) * 512 + fr * 64;
        #pragma unroll
        for (int nt = 0; nt < 4; ++nt)
            dst[nt * 16 + cl] = lnacc[nt * 4 + j];
    }
}

// ---------------------------------------------------------------------------
// block-wide sum over 256 threads (4 waves)
// ---------------------------------------------------------------------------
__device__ __forceinline__ float block_reduce_sum(float v, float* sRed) {
    #pragma unroll
    for (int m = 1; m < 64; m <<= 1) v += __shfl_xor(v, m, 64);
    int wave = threadIdx.x >> 6, lane = threadIdx.x & 63;
    __syncthreads();
    if (lane == 0) sRed[wave] = v;
    __syncthreads();
    return sRed[0] + sRed[1] + sRed[2] + sRed[3];
}

// ---------------------------------------------------------------------------
// Kernel R: reduce parts -> relu(sum/L) and gather concat -> X bf16 [256][1312]
// grid = 256 blocks (one per b), 256 threads
// ---------------------------------------------------------------------------
__global__ __launch_bounds__(256) void reduceX_kernel(
    const float* __restrict__ parts,
    const int* __restrict__ target_ad, const int* __restrict__ profile_feature,
    const float* __restrict__ context,
    const float* __restrict__ item_tables, const float* __restrict__ profile_tables,
    unsigned short* __restrict__ X)
{
    const int b = blockIdx.x, t = threadIdx.x;
    float s0 = 0.f, s1 = 0.f;
    for (int ch = 0; ch < NCH_; ++ch) {
        const float2 v = *(const float2*)(parts + ((size_t)(ch * 256 + b)) * 512 + t * 2);
        s0 += v.x; s1 += v.y;
    }
    X[b * TOWER_IN_ + t * 2]     = f2bf(fmaxf(s0 * 0.01f, 0.f));
    X[b * TOWER_IN_ + t * 2 + 1] = f2bf(fmaxf(s1 * 0.01f, 0.f));
    for (int cc = 512 + t; cc < TOWER_IN_; cc += 256) {
        float v;
        if (cc < 1024) { int j = cc - 512, f = j >> 6, e = j & 63;
            v = item_tables[((size_t)f * V_ + target_ad[b * 8 + f]) * 64 + e]; }
        else if (cc < 1280) { int j = cc - 1024, pp = j >> 6, e = j & 63;
            v = profile_tables[((size_t)pp * V_ + profile_feature[b * 4 + pp]) * 64 + e]; }
        else v = context[b * 32 + (cc - 1280)];
        X[b * TOWER_IN_ + cc] = f2bf(v);
    }
}

// ---------------------------------------------------------------------------
// Kernel G: generic bf16 MFMA GEMM  C[m][n] = A[m][:K] . Bw[n][:K] + bias[n]
// grid = (N/64, M/16), 256 threads (4 waves; wave = 16-col subtile)
// ---------------------------------------------------------------------------
__global__ __launch_bounds__(256) void gemm_kernel(
    const unsigned short* __restrict__ A, const unsigned short* __restrict__ Bw,
    const float* __restrict__ bias, float* __restrict__ C, int K, int N)
{
    const int t = threadIdx.x;
    const int wv = t >> 6, lane = t & 63, quad = lane >> 4, cl = lane & 15;
    const int n0 = blockIdx.x * 64 + wv * 16;
    const int m0 = blockIdx.y * 16;
    f4v acc = {0.f, 0.f, 0.f, 0.f};
    const unsigned short* arow = A + (size_t)(m0 + cl) * K + quad * 8;
    const unsigned short* brow = Bw + (size_t)(n0 + cl) * K + quad * 8;
    for (int k0 = 0; k0 < K; k0 += 32) {
        bf8v a = *(const bf8v*)(arow + k0);
        bf8v b = *(const bf8v*)(brow + k0);
        acc = __builtin_amdgcn_mfma_f32_16x16x32_bf16(a, b, acc, 0, 0, 0);
    }
    float bv = bias[n0 + cl];
    #pragma unroll
    for (int j = 0; j < 4; ++j)
        C[(size_t)(m0 + quad * 4 + j) * N + n0 + cl] = acc[j] + bv;
}

// ---------------------------------------------------------------------------
// Kernel N: rowwise LN + ReLU -> bf16.  grid = 256 (one row per block).
// ---------------------------------------------------------------------------
__global__ __launch_bounds__(256) void ln_relu_kernel(
    const float* __restrict__ C, const float* __restrict__ g,
    const float* __restrict__ bb, unsigned short* __restrict__ Hx, int N)
{
    __shared__ float sRed[4];
    const int b = blockIdx.x, t = threadIdx.x;
    float s = 0.f, s2 = 0.f;
    for (int j = t; j < N; j += 256) { float x = C[(size_t)b * N + j]; s += x; s2 += x * x; }
    s  = block_reduce_sum(s,  sRed);
    __syncthreads();
    s2 = block_reduce_sum(s2, sRed);
    float invN = 1.f / (float)N;
    float mean = s * invN;
    float var  = s2 * invN - mean * mean;
    float rst  = rsqrtf(fmaxf(var, 0.f) + LN_EPS);
    for (int j = t; j < N; j += 256) {
        float x = C[(size_t)b * N + j];
        Hx[(size_t)b * N + j] = f2bf(fmaxf((x - mean) * rst * g[j] + bb[j], 0.f));
    }
}

// ---------------------------------------------------------------------------
// Kernel F: final LN + ReLU + dot(w4) + sigmoid.  grid = 256.
// ---------------------------------------------------------------------------
__global__ __launch_bounds__(256) void final_kernel(
    const float* __restrict__ C3, const float* __restrict__ g3,
    const float* __restrict__ bb3, const float* __restrict__ w4,
    const float* __restrict__ b4, float* __restrict__ out)
{
    __shared__ float sRed[4];
    const int b = blockIdx.x, t = threadIdx.x;
    float x = C3[b * 256 + t];
    float s = block_reduce_sum(x, sRed);
    float mean = s * (1.f / 256.f);
    float d = x - mean;
    __syncthreads();
    float q = block_reduce_sum(d * d, sRed);
    float rst = rsqrtf(q * (1.f / 256.f) + LN_EPS);
    float h = fmaxf(d * rst * g3[t] + bb3[t], 0.f);
    __syncthreads();
    float p = block_reduce_sum(h * w4[t], sRed);
    if (t == 0) out[b] = 1.f / (1.f + expf(-(p + b4[0])));
}

// ---------------------------------------------------------------------------
extern "C" void kernel_launch(void* const* d_in, const int* in_sizes, int n_in,
                              void* d_out, int out_size, void* d_ws, size_t ws_size,
                              hipStream_t stream)
{
    (void)in_sizes; (void)n_in; (void)out_size; (void)ws_size;
    const int*   target_ad       = (const int*)d_in[0];
    const int*   ubs_feature     = (const int*)d_in[1];
    const int*   profile_feature = (const int*)d_in[2];
    const float* context         = (const float*)d_in[3];
    const float* item_tables     = (const float*)d_in[4];
    const float* profile_tables  = (const float*)d_in[5];
    const float* q_w   = (const float*)d_in[6];
    const float* k_w   = (const float*)d_in[7];
    const float* v_w   = (const float*)d_in[8];
    const float* lin_w = (const float*)d_in[9];
    const float* lin_b = (const float*)d_in[10];
    const float* ln_g  = (const float*)d_in[11];
    const float* ln_b  = (const float*)d_in[12];
    const float* t_w1  = (const float*)d_in[13];
    const float* t_b1  = (const float*)d_in[14];
    const float* t_g1  = (const float*)d_in[15];
    const float* t_bb1 = (const float*)d_in[16];
    const float* t_w2  = (const float*)d_in[17];
    const float* t_b2  = (const float*)d_in[18];
    const float* t_g2  = (const float*)d_in[19];
    const float* t_bb2 = (const float*)d_in[20];
    const float* t_w3  = (const float*)d_in[21];
    const float* t_b3  = (const float*)d_in[22];
    const float* t_g3  = (const float*)d_in[23];
    const float* t_bb3 = (const float*)d_in[24];
    const float* t_w4  = (const float*)d_in[25];
    const float* t_b4  = (const float*)d_in[26];

    char* ws = (char*)d_ws;
    unsigned short* wsMT = (unsigned short*)(ws);              // 3,276,800
    unsigned short* wsWT = (unsigned short*)(ws + 3276800);    // 3,276,800
    float* parts = (float*)(ws + 6553600);                     // 50*256*512*4 = 26,214,400
    // C/H buffers alias the parts region (parts fully consumed by reduceX first)
    float*          C1 = (float*)(ws + 6553600);               // 1,048,576
    unsigned short* H1 = (unsigned short*)(ws + 7602176);      //   524,288
    float*          C2 = (float*)(ws + 8126464);               //   524,288
    unsigned short* H2 = (unsigned short*)(ws + 8650752);      //   262,144
    float*          C3 = (float*)(ws + 8912896);               //   262,144 (ends 9,175,040)
    unsigned short* Wt1 = (unsigned short*)(ws + 32768000);    // 2,686,976
    unsigned short* Wt2 = (unsigned short*)(ws + 35454976);    // 1,048,576
    unsigned short* Wt3 = (unsigned short*)(ws + 36503552);    //   262,144
    unsigned short* X   = (unsigned short*)(ws + 36765696);    //   671,744 (ends 37,437,440)

    prep_kernel<<<1952, 256, 0, stream>>>(t_w1, t_w2, t_w3, Wt1, Wt2, Wt3);
    precomp_kernel<<<L_ * H_, 256, 0, stream>>>(q_w, k_w, v_w, lin_w, wsMT, wsWT);
    attn_kernel<<<NCH_ * 16, 512, 0, stream>>>(ubs_feature, item_tables, wsMT, wsWT,
                                               lin_b, ln_g, ln_b, parts);
    reduceX_kernel<<<B_, 256, 0, stream>>>(parts, target_ad, profile_feature, context,
                                           item_tables, profile_tables, X);
    gemm_kernel<<<dim3(16, 16), 256, 0, stream>>>(X,  Wt1, t_b1, C1, 1312, 1024);
    ln_relu_kernel<<<B_, 256, 0, stream>>>(C1, t_g1, t_bb1, H1, 1024);
    gemm_kernel<<<dim3(8, 16),  256, 0, stream>>>(H1, Wt2, t_b2, C2, 1024, 512);
    ln_relu_kernel<<<B_, 256, 0, stream>>>(C2, t_g2, t_bb2, H2, 512);
    gemm_kernel<<<dim3(4, 16),  256, 0, stream>>>(H2, Wt3, t_b3, C3, 512, 256);
    final_kernel<<<B_, 256, 0, stream>>>(C3, t_g3, t_bb3, t_w4, t_b4, (float*)d_out);
}

// Round 5
// 315.910 us; speedup vs baseline: 2.0111x; 1.3365x over previous
//
#include <hip/hip_runtime.h>
#include <hip/hip_bf16.h>

#define B_ 256
#define L_ 100
#define F_ 8
#define P_ 4
#define E_ 64
#define H_ 4
#define D_ 64
#define C_ 32
#define V_ 10000
#define TOWER_IN_ 1312
#define LN_EPS 0.001f
#define LCH_ 4    // l's per attention block
#define NCH_ 25   // number of l-chunks

typedef __attribute__((ext_vector_type(8))) short bf8v;   // 8 bf16 (4 VGPRs)
typedef __attribute__((ext_vector_type(4))) float f4v;    // 4 f32 acc

__device__ __forceinline__ unsigned short f2bf(float x) {
    __hip_bfloat16 h = __float2bfloat16(x);
    return __builtin_bit_cast(unsigned short, h);
}

// ---------------------------------------------------------------------------
// Kernel P: precompute MT[l,h][o][e] = (Qh Kh^T)^T and WT[l,h][o][e] = (Vh Lh)^T
// in bf16.  grid = 400 blocks, 256 threads.   (verified R3/R4)
// ---------------------------------------------------------------------------
__global__ __launch_bounds__(256) void precomp_kernel(
    const float* __restrict__ q_w, const float* __restrict__ k_w,
    const float* __restrict__ v_w, const float* __restrict__ lin_w,
    unsigned short* __restrict__ wsMT, unsigned short* __restrict__ wsWT)
{
    __shared__ float sA[64][65];
    __shared__ float sB[64][65];
    const int t = threadIdx.x;
    const int l = blockIdx.x >> 2;
    const int h = blockIdx.x & 3;
    const size_t obase = (size_t)(l * 4 + h) * 4096;

    for (int i = 0; i < 16; ++i) {
        int idx = t + i * 256;
        int e = idx >> 6, d = idx & 63;
        sA[e][d] = q_w[(l * 64 + e) * 256 + h * 64 + d];
        sB[e][d] = k_w[(l * 64 + e) * 256 + h * 64 + d];
    }
    __syncthreads();
    for (int i = 0; i < 16; ++i) {
        int idx = t + i * 256;
        int o = idx >> 6, e = idx & 63;
        float s = 0.f;
        #pragma unroll 8
        for (int d = 0; d < 64; ++d) s += sA[e][d] * sB[o][d];
        wsMT[obase + idx] = f2bf(s);
    }
    __syncthreads();

    for (int i = 0; i < 16; ++i) {
        int idx = t + i * 256;
        int dd = idx >> 6, oo = idx & 63;
        sB[dd][oo] = lin_w[l * 16384 + (h * 64 + dd) * 64 + oo];
    }
    for (int i = 0; i < 16; ++i) {
        int idx = t + i * 256;
        int e = idx >> 6, d = idx & 63;
        sA[e][d] = v_w[(l * 64 + e) * 256 + h * 64 + d];
    }
    __syncthreads();
    for (int i = 0; i < 16; ++i) {
        int idx = t + i * 256;
        int o = idx >> 6, e = idx & 63;
        float s = 0.f;
        #pragma unroll 8
        for (int d = 0; d < 64; ++d) s += sA[e][d] * sB[d][o];
        wsWT[obase + idx] = f2bf(s);
    }
}

// ---------------------------------------------------------------------------
// Kernel W: transpose tower weights to bf16 [n][k].  grid = 1952, 256 thr.
// ---------------------------------------------------------------------------
__global__ __launch_bounds__(256) void prep_kernel(
    const float* __restrict__ w1, const float* __restrict__ w2,
    const float* __restrict__ w3,
    unsigned short* __restrict__ Wt1, unsigned short* __restrict__ Wt2,
    unsigned short* __restrict__ Wt3)
{
    __shared__ float tile[32][33];
    int bx = blockIdx.x;
    const float* src; unsigned short* dst; int K, N, tk, tn;
    if (bx < 1312)      { src = w1; dst = Wt1; K = 1312; N = 1024; tk = bx / 32;  tn = bx % 32; }
    else if (bx < 1824) { int i = bx - 1312; src = w2; dst = Wt2; K = 1024; N = 512; tk = i / 16; tn = i % 16; }
    else                { int i = bx - 1824; src = w3; dst = Wt3; K = 512;  N = 256; tk = i / 8;  tn = i % 8; }
    const int k0 = tk * 32, n0 = tn * 32;
    const int rr = threadIdx.x >> 5, cc = threadIdx.x & 31;
    #pragma unroll
    for (int i = 0; i < 4; ++i) {
        int r = rr * 4 + i;
        tile[r][cc] = src[(size_t)(k0 + r) * N + n0 + cc];
    }
    __syncthreads();
    #pragma unroll
    for (int i = 0; i < 4; ++i) {
        int r = rr * 4 + i;
        dst[(size_t)(n0 + r) * K + k0 + cc] = f2bf(tile[cc][r]);
    }
}

// ---------------------------------------------------------------------------
// Kernel A: fused attention, MFMA for everything but softmax.
// grid = NCH_*32 blocks (block = 8 b's x LCH_ l's), 256 threads = 4 waves.
// Per l, per half (2 heads):
//   phase A: T = UE@M (waves 0,1) and Zt = (UE@W)^T-staged (waves 2,3)
//   scores:  S = T@UE^T per 2-b pair (MFMA, diag 16x16), softmax in-register,
//            attw written as block-diagonal A-operand (zeros cross-b)
//   PV:      accO += Ablk @ Zt   (one K=32 MFMA per 16-col tile)
// LN per row at end of l; atomicAdd into ubs_acc at end.
// ---------------------------------------------------------------------------
__global__ __launch_bounds__(256, 3) void attn_kernel(
    const int* __restrict__ ubs_feature, const float* __restrict__ item_tables,
    const unsigned short* __restrict__ wsMT, const unsigned short* __restrict__ wsWT,
    const float* __restrict__ lin_b, const float* __restrict__ ln_g,
    const float* __restrict__ ln_b, float* __restrict__ ubs_acc)
{
    __shared__ __align__(16) unsigned short sUE[64][72];       // rows=b_loc*8+f
    __shared__ __align__(16) unsigned short sT[64][136];       // cols=hl*64+e'
    __shared__ __align__(16) unsigned short sZt[4][64][32];    // [pair][e][k]
    __shared__ __align__(16) unsigned short sAblk[4][16][32];  // [pair][r][k]
    __shared__ float sLng[64], sLnb[64], sLinb[64];

    const int t = threadIdx.x;
    const int c = blockIdx.x >> 5;            // l-chunk 0..24
    const int b0 = (blockIdx.x & 31) * 8;
    const int wv = t >> 6, lane = t & 63, quad = lane >> 4, cl = lane & 15;
    const int grow = t >> 2, gseg = t & 3, ge0 = gseg * 16;   // gather mapping
    const int gbl = grow >> 3, gfq = grow & 7;

    if (t < 64) { sLng[t] = ln_g[t]; sLnb[t] = ln_b[t]; }

    float lnacc[16];
    #pragma unroll
    for (int i = 0; i < 16; ++i) lnacc[i] = 0.f;

    for (int li = 0; li < LCH_; ++li) {
        const int l = c * LCH_ + li;
        if (t >= 64 && t < 128) sLinb[t - 64] = lin_b[l * 64 + (t - 64)];

        // ---- gather UE rows (f32 -> bf16) ----
        {
            const int bg = b0 + gbl;
            const int vidx = ubs_feature[(bg * L_ + l) * F_ + gfq];
            const float* srcp = item_tables + ((size_t)gfq * V_ + vidx) * 64 + ge0;
            #pragma unroll
            for (int j = 0; j < 8; ++j) {
                float x0 = srcp[2 * j], x1 = srcp[2 * j + 1];
                unsigned u = (unsigned)f2bf(x0) | ((unsigned)f2bf(x1) << 16);
                *(unsigned*)&sUE[grow][ge0 + 2 * j] = u;
            }
        }
        __syncthreads();

        f4v accO[4];
        #pragma unroll
        for (int nt = 0; nt < 4; ++nt) accO[nt] = {0.f, 0.f, 0.f, 0.f};

        for (int half = 0; half < 2; ++half) {
            // ---- phase A: waves 0,1 -> T (h=hl); waves 2,3 -> Zt (h=hl) ----
            {
                const int role = wv >> 1;     // 0=T, 1=Z
                const int hl = wv & 1;
                const unsigned short* Bsrc =
                    (role == 0 ? wsMT : wsWT) + (size_t)(l * 4 + half * 2 + hl) * 4096;
                bf8v bfrag[4][2];
                #pragma unroll
                for (int nt = 0; nt < 4; ++nt)
                    #pragma unroll
                    for (int k2 = 0; k2 < 2; ++k2)
                        bfrag[nt][k2] = *(const bf8v*)(Bsrc + (nt * 16 + cl) * 64 + k2 * 32 + quad * 8);
                #pragma unroll
                for (int m = 0; m < 4; ++m) {
                    bf8v a0 = *(const bf8v*)&sUE[m * 16 + cl][quad * 8];
                    bf8v a1 = *(const bf8v*)&sUE[m * 16 + cl][32 + quad * 8];
                    #pragma unroll
                    for (int nt = 0; nt < 4; ++nt) {
                        f4v acc = {0.f, 0.f, 0.f, 0.f};
                        acc = __builtin_amdgcn_mfma_f32_16x16x32_bf16(a0, bfrag[nt][0], acc, 0, 0, 0);
                        acc = __builtin_amdgcn_mfma_f32_16x16x32_bf16(a1, bfrag[nt][1], acc, 0, 0, 0);
                        if (role == 0) {
                            #pragma unroll
                            for (int j = 0; j < 4; ++j)
                                sT[m * 16 + quad * 4 + j][hl * 64 + nt * 16 + cl] = f2bf(acc[j]);
                        } else {
                            // rows r=m*16+quad*4+j: pair=m, bloc=quad>>1, g=(quad&1)*4+j
                            ushort4 zp;
                            zp.x = f2bf(acc[0]); zp.y = f2bf(acc[1]);
                            zp.z = f2bf(acc[2]); zp.w = f2bf(acc[3]);
                            const int k0 = (quad >> 1) * 16 + hl * 8 + (quad & 1) * 4;
                            *(ushort4*)&sZt[m][nt * 16 + cl][k0] = zp;
                        }
                    }
                }
            }
            __syncthreads();

            // ---- scores + softmax + Ablk (wave = pair) ----
            {
                const int p = wv;
                const bool valid = (cl >> 3) == (quad >> 1);
                #pragma unroll
                for (int hl = 0; hl < 2; ++hl) {
                    bf8v a0 = *(const bf8v*)&sT[p * 16 + cl][hl * 64 + quad * 8];
                    bf8v a1 = *(const bf8v*)&sT[p * 16 + cl][hl * 64 + 32 + quad * 8];
                    bf8v u0 = *(const bf8v*)&sUE[p * 16 + cl][quad * 8];
                    bf8v u1 = *(const bf8v*)&sUE[p * 16 + cl][32 + quad * 8];
                    f4v acc = {0.f, 0.f, 0.f, 0.f};
                    acc = __builtin_amdgcn_mfma_f32_16x16x32_bf16(a0, u0, acc, 0, 0, 0);
                    acc = __builtin_amdgcn_mfma_f32_16x16x32_bf16(a1, u1, acc, 0, 0, 0);
                    const int kk = hl * 8 + (cl & 7) + (cl >> 3) * 16;
                    #pragma unroll
                    for (int j = 0; j < 4; ++j) {
                        float v = acc[j] * 0.125f;
                        float mx = v;
                        mx = fmaxf(mx, __shfl_xor(mx, 1));
                        mx = fmaxf(mx, __shfl_xor(mx, 2));
                        mx = fmaxf(mx, __shfl_xor(mx, 4));
                        float ex = __expf(v - mx);
                        float sm = ex;
                        sm += __shfl_xor(sm, 1);
                        sm += __shfl_xor(sm, 2);
                        sm += __shfl_xor(sm, 4);
                        float aw = valid ? ex / sm : 0.f;
                        sAblk[p][quad * 4 + j][kk] = f2bf(aw);
                    }
                }
            }
            __syncthreads();

            // ---- PV: accO += Ablk @ Zt (wave = pair) ----
            {
                const int p = wv;
                bf8v a0 = *(const bf8v*)&sAblk[p][cl][quad * 8];
                #pragma unroll
                for (int nt = 0; nt < 4; ++nt) {
                    bf8v bz = *(const bf8v*)&sZt[p][nt * 16 + cl][quad * 8];
                    accO[nt] = __builtin_amdgcn_mfma_f32_16x16x32_bf16(a0, bz, accO[nt], 0, 0, 0);
                }
            }
            __syncthreads();
        }

        // ---- +lin_b, LayerNorm per row over 64 cols, accumulate over l ----
        {
            float x[16];
            #pragma unroll
            for (int nt = 0; nt < 4; ++nt)
                #pragma unroll
                for (int j = 0; j < 4; ++j)
                    x[nt * 4 + j] = accO[nt][j] + sLinb[nt * 16 + cl];
            #pragma unroll
            for (int j = 0; j < 4; ++j) {
                float s = x[j] + x[4 + j] + x[8 + j] + x[12 + j];
                #pragma unroll
                for (int m = 1; m < 16; m <<= 1) s += __shfl_xor(s, m);
                float mean = s * (1.f / 64.f);
                float q = 0.f;
                #pragma unroll
                for (int nt = 0; nt < 4; ++nt) { float d = x[nt * 4 + j] - mean; q += d * d; }
                #pragma unroll
                for (int m = 1; m < 16; m <<= 1) q += __shfl_xor(q, m);
                float rst = rsqrtf(q * (1.f / 64.f) + LN_EPS);
                #pragma unroll
                for (int nt = 0; nt < 4; ++nt) {
                    int col = nt * 16 + cl;
                    lnacc[nt * 4 + j] += (x[nt * 4 + j] - mean) * rst * sLng[col] + sLnb[col];
                }
            }
        }
        __syncthreads();
    }

    // ---- accumulate into ubs_acc ----
    #pragma unroll
    for (int j = 0; j < 4; ++j) {
        const int row = wv * 16 + quad * 4 + j;
        const int b = b0 + (row >> 3), f = row & 7;
        #pragma unroll
        for (int nt = 0; nt < 4; ++nt)
            atomicAdd(&ubs_acc[(size_t)b * 512 + f * 64 + nt * 16 + cl], lnacc[nt * 4 + j]);
    }
}

// ---------------------------------------------------------------------------
// block-wide sum over 256 threads (4 waves)
// ---------------------------------------------------------------------------
__device__ __forceinline__ float block_reduce_sum(float v, float* sRed) {
    #pragma unroll
    for (int m = 1; m < 64; m <<= 1) v += __shfl_xor(v, m, 64);
    int wave = threadIdx.x >> 6, lane = threadIdx.x & 63;
    __syncthreads();
    if (lane == 0) sRed[wave] = v;
    __syncthreads();
    return sRed[0] + sRed[1] + sRed[2] + sRed[3];
}

// ---------------------------------------------------------------------------
// Kernel R: ubs = relu(acc/L) and gather concat -> X bf16 [256][1312]
// ---------------------------------------------------------------------------
__global__ __launch_bounds__(256) void reduceX_kernel(
    const float* __restrict__ ubs_acc,
    const int* __restrict__ target_ad, const int* __restrict__ profile_feature,
    const float* __restrict__ context,
    const float* __restrict__ item_tables, const float* __restrict__ profile_tables,
    unsigned short* __restrict__ X)
{
    const int b = blockIdx.x, t = threadIdx.x;
    const float2 v = *(const float2*)(ubs_acc + (size_t)b * 512 + t * 2);
    X[b * TOWER_IN_ + t * 2]     = f2bf(fmaxf(v.x * 0.01f, 0.f));
    X[b * TOWER_IN_ + t * 2 + 1] = f2bf(fmaxf(v.y * 0.01f, 0.f));
    for (int cc = 512 + t; cc < TOWER_IN_; cc += 256) {
        float x;
        if (cc < 1024) { int j = cc - 512, f = j >> 6, e = j & 63;
            x = item_tables[((size_t)f * V_ + target_ad[b * 8 + f]) * 64 + e]; }
        else if (cc < 1280) { int j = cc - 1024, pp = j >> 6, e = j & 63;
            x = profile_tables[((size_t)pp * V_ + profile_feature[b * 4 + pp]) * 64 + e]; }
        else x = context[b * 32 + (cc - 1280)];
        X[b * TOWER_IN_ + cc] = f2bf(x);
    }
}

// ---------------------------------------------------------------------------
// Kernel G: generic bf16 MFMA GEMM  C[m][n] = A[m][:K] . Bw[n][:K] + bias[n]
// grid = (N/64, M/16), 256 threads (4 waves; wave = 16-col subtile)
// ---------------------------------------------------------------------------
__global__ __launch_bounds__(256) void gemm_kernel(
    const unsigned short* __restrict__ A, const unsigned short* __restrict__ Bw,
    const float* __restrict__ bias, float* __restrict__ C, int K, int N)
{
    const int t = threadIdx.x;
    const int wv = t >> 6, lane = t & 63, quad = lane >> 4, cl = lane & 15;
    const int n0 = blockIdx.x * 64 + wv * 16;
    const int m0 = blockIdx.y * 16;
    f4v acc = {0.f, 0.f, 0.f, 0.f};
    const unsigned short* arow = A + (size_t)(m0 + cl) * K + quad * 8;
    const unsigned short* brow = Bw + (size_t)(n0 + cl) * K + quad * 8;
    for (int k0 = 0; k0 < K; k0 += 32) {
        bf8v a = *(const bf8v*)(arow + k0);
        bf8v b = *(const bf8v*)(brow + k0);
        acc = __builtin_amdgcn_mfma_f32_16x16x32_bf16(a, b, acc, 0, 0, 0);
    }
    float bv = bias[n0 + cl];
    #pragma unroll
    for (int j = 0; j < 4; ++j)
        C[(size_t)(m0 + quad * 4 + j) * N + n0 + cl] = acc[j] + bv;
}

// ---------------------------------------------------------------------------
// Kernel N: rowwise LN + ReLU -> bf16.  grid = 256 (one row per block).
// ---------------------------------------------------------------------------
__global__ __launch_bounds__(256) void ln_relu_kernel(
    const float* __restrict__ C, const float* __restrict__ g,
    const float* __restrict__ bb, unsigned short* __restrict__ Hx, int N)
{
    __shared__ float sRed[4];
    const int b = blockIdx.x, t = threadIdx.x;
    float s = 0.f, s2 = 0.f;
    for (int j = t; j < N; j += 256) { float x = C[(size_t)b * N + j]; s += x; s2 += x * x; }
    s  = block_reduce_sum(s,  sRed);
    __syncthreads();
    s2 = block_reduce_sum(s2, sRed);
    float invN = 1.f / (float)N;
    float mean = s * invN;
    float var  = s2 * invN - mean * mean;
    float rst  = rsqrtf(fmaxf(var, 0.f) + LN_EPS);
    for (int j = t; j < N; j += 256) {
        float x = C[(size_t)b * N + j];
        Hx[(size_t)b * N + j] = f2bf(fmaxf((x - mean) * rst * g[j] + bb[j], 0.f));
    }
}

// ---------------------------------------------------------------------------
// Kernel F: final LN + ReLU + dot(w4) + sigmoid.  grid = 256.
// ---------------------------------------------------------------------------
__global__ __launch_bounds__(256) void final_kernel(
    const float* __restrict__ C3, const float* __restrict__ g3,
    const float* __restrict__ bb3, const float* __restrict__ w4,
    const float* __restrict__ b4, float* __restrict__ out)
{
    __shared__ float sRed[4];
    const int b = blockIdx.x, t = threadIdx.x;
    float x = C3[b * 256 + t];
    float s = block_reduce_sum(x, sRed);
    float mean = s * (1.f / 256.f);
    float d = x - mean;
    __syncthreads();
    float q = block_reduce_sum(d * d, sRed);
    float rst = rsqrtf(q * (1.f / 256.f) + LN_EPS);
    float h = fmaxf(d * rst * g3[t] + bb3[t], 0.f);
    __syncthreads();
    float p = block_reduce_sum(h * w4[t], sRed);
    if (t == 0) out[b] = 1.f / (1.f + expf(-(p + b4[0])));
}

// ---------------------------------------------------------------------------
extern "C" void kernel_launch(void* const* d_in, const int* in_sizes, int n_in,
                              void* d_out, int out_size, void* d_ws, size_t ws_size,
                              hipStream_t stream)
{
    (void)in_sizes; (void)n_in; (void)out_size; (void)ws_size;
    const int*   target_ad       = (const int*)d_in[0];
    const int*   ubs_feature     = (const int*)d_in[1];
    const int*   profile_feature = (const int*)d_in[2];
    const float* context         = (const float*)d_in[3];
    const float* item_tables     = (const float*)d_in[4];
    const float* profile_tables  = (const float*)d_in[5];
    const float* q_w   = (const float*)d_in[6];
    const float* k_w   = (const float*)d_in[7];
    const float* v_w   = (const float*)d_in[8];
    const float* lin_w = (const float*)d_in[9];
    const float* lin_b = (const float*)d_in[10];
    const float* ln_g  = (const float*)d_in[11];
    const float* ln_b  = (const float*)d_in[12];
    const float* t_w1  = (const float*)d_in[13];
    const float* t_b1  = (const float*)d_in[14];
    const float* t_g1  = (const float*)d_in[15];
    const float* t_bb1 = (const float*)d_in[16];
    const float* t_w2  = (const float*)d_in[17];
    const float* t_b2  = (const float*)d_in[18];
    const float* t_g2  = (const float*)d_in[19];
    const float* t_bb2 = (const float*)d_in[20];
    const float* t_w3  = (const float*)d_in[21];
    const float* t_b3  = (const float*)d_in[22];
    const float* t_g3  = (const float*)d_in[23];
    const float* t_bb3 = (const float*)d_in[24];
    const float* t_w4  = (const float*)d_in[25];
    const float* t_b4  = (const float*)d_in[26];

    char* ws = (char*)d_ws;
    unsigned short* wsMT = (unsigned short*)(ws);              //  3,276,800
    unsigned short* wsWT = (unsigned short*)(ws +  3276800);   //  3,276,800
    float* ubs_acc       = (float*)         (ws +  6553600);   //    524,288
    unsigned short* Wt1  = (unsigned short*)(ws +  7077888);   //  2,686,976
    unsigned short* Wt2  = (unsigned short*)(ws +  9764864);   //  1,048,576
    unsigned short* Wt3  = (unsigned short*)(ws + 10813440);   //    262,144
    unsigned short* X    = (unsigned short*)(ws + 11075584);   //    671,744
    float*          C1   = (float*)         (ws + 11747328);   //  1,048,576
    unsigned short* H1   = (unsigned short*)(ws + 12795904);   //    524,288
    float*          C2   = (float*)         (ws + 13320192);   //    524,288
    unsigned short* H2   = (unsigned short*)(ws + 13844480);   //    262,144
    float*          C3   = (float*)         (ws + 14106624);   //    262,144 (end 14,368,768)

    hipMemsetAsync(ubs_acc, 0, B_ * F_ * E_ * sizeof(float), stream);

    prep_kernel<<<1952, 256, 0, stream>>>(t_w1, t_w2, t_w3, Wt1, Wt2, Wt3);
    precomp_kernel<<<L_ * H_, 256, 0, stream>>>(q_w, k_w, v_w, lin_w, wsMT, wsWT);
    attn_kernel<<<NCH_ * 32, 256, 0, stream>>>(ubs_feature, item_tables, wsMT, wsWT,
                                               lin_b, ln_g, ln_b, ubs_acc);
    reduceX_kernel<<<B_, 256, 0, stream>>>(ubs_acc, target_ad, profile_feature, context,
                                           item_tables, profile_tables, X);
    gemm_kernel<<<dim3(16, 16), 256, 0, stream>>>(X,  Wt1, t_b1, C1, 1312, 1024);
    ln_relu_kernel<<<B_, 256, 0, stream>>>(C1, t_g1, t_bb1, H1, 1024);
    gemm_kernel<<<dim3(8, 16),  256, 0, stream>>>(H1, Wt2, t_b2, C2, 1024, 512);
    ln_relu_kernel<<<B_, 256, 0, stream>>>(C2, t_g2, t_bb2, H2, 512);
    gemm_kernel<<<dim3(4, 16),  256, 0, stream>>>(H2, Wt3, t_b3, C3, 512, 256);
    final_kernel<<<B_, 256, 0, stream>>>(C3, t_g3, t_bb3, t_w4, t_b4, (float*)d_out);
}